// Round 9
// baseline (444.110 us; speedup 1.0000x reference)
//
#include <hip/hip_runtime.h>
#include <cstdint>
#include <cstddef>

#define NT   8192
#define DIN  1024
#define DFF  4096
#define DOUT 1024
#define NEXP 8

typedef float  f32x4v __attribute__((ext_vector_type(4)));
typedef short  s16x8  __attribute__((ext_vector_type(8)));
typedef short  s16x4  __attribute__((ext_vector_type(4)));

__device__ __forceinline__ ushort f2bf(float f) {
  union { float f; uint32_t u; } c; c.f = f;
  uint32_t u = c.u;
  return (ushort)((u + 0x7fffu + ((u >> 16) & 1u)) >> 16);  // RNE
}
__device__ __forceinline__ float bf2f(ushort h) {
  union { uint32_t u; float f; } c; c.u = ((uint32_t)h) << 16; return c.f;
}

// ---------------- router: 1 block = 64 tokens, block-level atomic reduction --
__global__ __launch_bounds__(256) void router_kernel(
    const float* __restrict__ x, const float* __restrict__ sw,
    const float* __restrict__ sb,
    int* __restrict__ routes, int* __restrict__ posArr,
    float* __restrict__ pmaxArr,
    int* __restrict__ cnt, float* __restrict__ probsum) {
  __shared__ int   sRoute[64];
  __shared__ float sProb[4][NEXP];
  __shared__ int   sBase[NEXP];

  const int lane = threadIdx.x & 63;
  const int w    = threadIdx.x >> 6;
  const int t0   = blockIdx.x * 64;

  float bias[NEXP];
#pragma unroll
  for (int e = 0; e < NEXP; e++) bias[e] = sb[e];

  float wprob[NEXP];
#pragma unroll
  for (int e = 0; e < NEXP; e++) wprob[e] = 0.0f;

  for (int k = 0; k < 16; k++) {
    const int t = t0 + w * 16 + k;
    const float* xr = x + (size_t)t * DIN;
    float acc[NEXP];
#pragma unroll
    for (int e = 0; e < NEXP; e++) acc[e] = 0.0f;
#pragma unroll
    for (int it = 0; it < DIN / 64; it++) {
      const int i = it * 64 + lane;
      const float xv = xr[i];
      const float4 s0 = *(const float4*)(sw + (size_t)i * NEXP);
      const float4 s1 = *(const float4*)(sw + (size_t)i * NEXP + 4);
      acc[0] += xv * s0.x; acc[1] += xv * s0.y; acc[2] += xv * s0.z; acc[3] += xv * s0.w;
      acc[4] += xv * s1.x; acc[5] += xv * s1.y; acc[6] += xv * s1.z; acc[7] += xv * s1.w;
    }
#pragma unroll
    for (int e = 0; e < NEXP; e++) {
#pragma unroll
      for (int off = 32; off > 0; off >>= 1) acc[e] += __shfl_xor(acc[e], off, 64);
    }
    float m = acc[0] + bias[0]; int am = 0;
    float lg[NEXP];
#pragma unroll
    for (int e = 0; e < NEXP; e++) {
      lg[e] = acc[e] + bias[e];
      if (lg[e] > m) { m = lg[e]; am = e; }
    }
    float esum = 0.0f;
    float pe[NEXP];
#pragma unroll
    for (int e = 0; e < NEXP; e++) { pe[e] = __expf(lg[e] - m); esum += pe[e]; }
    const float inv = 1.0f / esum;
#pragma unroll
    for (int e = 0; e < NEXP; e++) wprob[e] += pe[e] * inv;
    if (lane == 0) {
      routes[t] = am;
      pmaxArr[t] = inv;           // pe[am] == 1 -> pmax = 1/esum
      sRoute[w * 16 + k] = am;
    }
  }
  if (lane == 0) {
#pragma unroll
    for (int e = 0; e < NEXP; e++) sProb[w][e] = wprob[e];
  }
  __syncthreads();

  const int tid = threadIdx.x;
  if (tid < NEXP) {
    float s = sProb[0][tid] + sProb[1][tid] + sProb[2][tid] + sProb[3][tid];
    atomicAdd(&probsum[tid], s);
    int c = 0;
#pragma unroll
    for (int j = 0; j < 64; j++) c += (sRoute[j] == tid);
    sBase[tid] = atomicAdd(&cnt[tid], c);
  }
  __syncthreads();

  if (tid < 64) {
    const int r = sRoute[tid];
    int rank = 0;
    for (int j = 0; j < 64; j++) rank += (j < tid) & (sRoute[j] == r);
    posArr[t0 + tid] = sBase[r] + rank;
  }
}

// ---------------- offsets (exclusive scan of 8) + aux loss -------------------
__global__ void offsets_aux_kernel(const int* __restrict__ cnt, const float* __restrict__ probsum,
                                   int* __restrict__ offsets, float* __restrict__ auxout) {
  if (threadIdx.x == 0) {
    int o = 0; float aux = 0.0f;
    for (int e = 0; e < NEXP; e++) {
      offsets[e] = o; o += cnt[e];
      aux += (float)cnt[e] * probsum[e];
    }
    offsets[NEXP] = o;
    auxout[0] = aux * ((float)NEXP / (float)NT);
  }
}

// ---------------- gather tokens into expert-contiguous bf16 rows -------------
__global__ void gather_kernel(const float* __restrict__ x, const int* __restrict__ routes,
                              const int* __restrict__ posArr, const int* __restrict__ offsets,
                              int* __restrict__ perm, ushort* __restrict__ Xg) {
  const int lane = threadIdx.x & 63;
  const int t = (blockIdx.x * blockDim.x + threadIdx.x) >> 6;
  if (t >= NT) return;
  const int slot = offsets[routes[t]] + posArr[t];
  if (lane == 0) perm[slot] = t;
  const float* src = x + (size_t)t * DIN;
  ushort* dst = Xg + (size_t)slot * DIN;
#pragma unroll
  for (int half = 0; half < 2; half++) {
    int i = half * 512 + lane * 8;
    float4 v0 = *(const float4*)(src + i);
    float4 v1 = *(const float4*)(src + i + 4);
    s16x8 p;
    p[0] = (short)f2bf(v0.x); p[1] = (short)f2bf(v0.y);
    p[2] = (short)f2bf(v0.z); p[3] = (short)f2bf(v0.w);
    p[4] = (short)f2bf(v1.x); p[5] = (short)f2bf(v1.y);
    p[6] = (short)f2bf(v1.z); p[7] = (short)f2bf(v1.w);
    *(s16x8*)(dst + i) = p;
  }
}

// ---------------- transpose + fp32->bf16: [E][K][N] -> [E][N][K] -------------
__global__ void transpose_cvt_kernel(const float* __restrict__ src, ushort* __restrict__ dst,
                                     const int K, const int N) {
  __shared__ float tile[64][65];
  const int ntn = N >> 6;
  const int ntk = K >> 6;
  int b = blockIdx.x;
  const int tn = b % ntn; b /= ntn;
  const int tk = b % ntk; const int e = b / ntk;
  const float* s = src + ((size_t)e * K + (size_t)tk * 64) * N + (size_t)tn * 64;
  const int c4 = (threadIdx.x & 15) * 4;
  const int r0 = threadIdx.x >> 4;  // 0..15
#pragma unroll
  for (int p = 0; p < 4; p++) {
    const int row = r0 + p * 16;
    float4 v = *(const float4*)(s + (size_t)row * N + c4);
    tile[row][c4 + 0] = v.x; tile[row][c4 + 1] = v.y;
    tile[row][c4 + 2] = v.z; tile[row][c4 + 3] = v.w;
  }
  __syncthreads();
  ushort* d = dst + ((size_t)e * N + (size_t)tn * 64) * K + (size_t)tk * 64;
#pragma unroll
  for (int p = 0; p < 4; p++) {
    const int nrow = r0 + p * 16;
    s16x4 o;
    o[0] = (short)f2bf(tile[c4 + 0][nrow]);
    o[1] = (short)f2bf(tile[c4 + 1][nrow]);
    o[2] = (short)f2bf(tile[c4 + 2][nrow]);
    o[3] = (short)f2bf(tile[c4 + 3][nrow]);
    *(s16x4*)(d + (size_t)nrow * K + c4) = o;
  }
}

#define GLD16(g, l)                                                                        \
  __builtin_amdgcn_global_load_lds((const __attribute__((address_space(1))) uint32_t*)(g), \
                                   (__attribute__((address_space(3))) uint32_t*)(l), 16, 0, 0)

#define SBAR()   asm volatile("s_barrier" ::: "memory")
#define WAITV(n) asm volatile("s_waitcnt vmcnt(" #n ")" ::: "memory")

// ===== 256x(NBH*128) / BK=64 / 8-wave / 2-PHASE single-barrier grouped GEMM ==
// T3-minimum recipe (m230/m248: 655-682 TF on this exact grouped shape):
// per K-tile: STAGE(next buf) -> ALL ds_reads -> ALL 64/32 MFMA (setprio) ->
// vmcnt(0) -> s_barrier. ONE barrier + ONE vmcnt per K-tile: the whole tile is
// a single basic block so the compiler emits fine-grained lgkmcnt(4/3/1/0)
// interleave (m97 asm evidence) — early waves MFMA while LDS port serves
// later waves. (R5-R8's 8-barrier sub-phase loop forced port/MFMA alternation
// -> MfmaUtil pinned at 20%.)
// EPI==0 (GEMM1): flat grid, expert->XCD chunked swizzle (FETCH 200->52MB, R8).
// EPI==3 (GEMM2): split-K=2, grid (N/(NBH*128), my, 16): e=z&7, part=z>>3;
//   part0 -> Y fp32 scatter w/ bias+pmax; part1 -> P1 bf16 partial.
// LDS swizzle: (row, kslot16B) at phys kslot^(row&7), via pre-swizzled global
// source + linear LDS dest (rule #21); 0 bank conflicts (R3+).
// NOTE: launch_bounds min-waves/EU MUST be 1 (",2" caps 128 VGPR -> acc spill).
template <int KDIM, int EPI, int NBH>
__global__ __launch_bounds__(512, 1) void moe_gemm2p_kernel(
    const ushort* __restrict__ A,   // [slots][LDK] bf16 expert-contiguous
    const ushort* __restrict__ BT,  // [E][N][LDK] bf16
    const float* __restrict__ bias, // [E][N]
    const int* __restrict__ offsets,
    ushort* __restrict__ Hout,      // EPI==0: [slots][N] bf16 (relu)
    float* __restrict__ Y,          // EPI==3 part0: [NT][N] fp32 scatter
    ushort* __restrict__ P1,        // EPI==3 part1: [slots][N] bf16 partial
    const int* __restrict__ perm, const float* __restrict__ pmaxArr,
    const int N, const int LDK) {
  __shared__ ushort sA[2][2][8192];     // [buf][row-half][128x64 swz]
  __shared__ ushort sB[2][NBH][8192];   // [buf][n-half]
  int e, bx, by, part;
  if constexpr (EPI == 0) {
    const int logical = ((blockIdx.x & 7) << 7) + (blockIdx.x >> 3);
    e = logical >> 7;
    bx = (logical & 127) >> 3;
    by = logical & 7;
    part = 0;
  } else {
    bx = blockIdx.x; by = blockIdx.y;
    e = blockIdx.z & 7; part = blockIdx.z >> 3;
  }
  const size_t kofs = (size_t)part * KDIM;
  const int mlimit = offsets[e + 1];
  const int m0 = offsets[e] + by * 256;
  if (m0 >= mlimit) return;
  const int n0 = bx * (NBH * 128);
  const int tid = threadIdx.x;
  const int lane = tid & 63;
  const int wid = tid >> 6;
  const int wr = wid >> 2;   // 0..1 : row 64-group within each 128-row half
  const int wc = wid & 3;    // 0..3 : col 32-group within each 128-col half
  const int rsel = lane & 15;
  const int lhi = lane >> 4; // 0..3

  // staging: thread covers bytes tid*16 (+8192B) of each 16KB half-tile.
  const int srow = wid * 8 + (lane >> 3);           // local row, chunk 0
  const int scol = ((lane & 7) ^ (lane >> 3)) * 8;  // pre-swizzled source col
  const ushort* gA = A + (size_t)(m0 + srow) * LDK + kofs + scol;
  const ushort* gB = BT + ((size_t)e * N + n0 + srow) * LDK + kofs + scol;
  const int ldst = tid * 8;  // elem offset; +4096 elems for rows +64
  const size_t LK = (size_t)LDK;

#define STAGE_T(buf, kt)                                                \
  do {                                                                  \
    const ushort* ga_ = gA + (size_t)(kt) * 64;                         \
    GLD16(ga_, &sA[buf][0][ldst]);                                      \
    GLD16(ga_ + 64 * LK, &sA[buf][0][ldst + 4096]);                     \
    GLD16(ga_ + 128 * LK, &sA[buf][1][ldst]);                           \
    GLD16(ga_ + 192 * LK, &sA[buf][1][ldst + 4096]);                    \
    const ushort* gb_ = gB + (size_t)(kt) * 64;                         \
    GLD16(gb_, &sB[buf][0][ldst]);                                      \
    GLD16(gb_ + 64 * LK, &sB[buf][0][ldst + 4096]);                     \
    if (NBH == 2) {                                                     \
      GLD16(gb_ + 128 * LK, &sB[buf][1][ldst]);                         \
      GLD16(gb_ + 192 * LK, &sB[buf][1][ldst + 4096]);                  \
    }                                                                   \
  } while (0)

  f32x4v acc[2][NBH][4][2];
#pragma unroll
  for (int i = 0; i < 2; i++)
#pragma unroll
    for (int j = 0; j < NBH; j++)
#pragma unroll
      for (int mf = 0; mf < 4; mf++)
#pragma unroll
        for (int nf = 0; nf < 2; nf++) acc[i][j][mf][nf] = (f32x4v)0.0f;

  const int rsw = rsel & 7;
  const int sw0 = ((lhi) ^ rsw) * 8;       // phys 16B-slot for k-step 0
  const int sw1 = ((4 + lhi) ^ rsw) * 8;   // phys 16B-slot for k-step 1
  int arow[4], brow[2];
#pragma unroll
  for (int mf = 0; mf < 4; mf++) arow[mf] = (wr * 64 + mf * 16 + rsel) * 64;
#pragma unroll
  for (int nf = 0; nf < 2; nf++) brow[nf] = (wc * 32 + nf * 16 + rsel) * 64;

  s16x8 a[4][2], b0[2][2], b1[2][2];

#define LDA(buf, h)                                                    \
  do {                                                                 \
    _Pragma("unroll") for (int mf = 0; mf < 4; mf++) {                 \
      a[mf][0] = *(const s16x8*)&sA[buf][h][arow[mf] + sw0];           \
      a[mf][1] = *(const s16x8*)&sA[buf][h][arow[mf] + sw1];           \
    }                                                                  \
  } while (0)
#define LDB(dst, buf, h)                                               \
  do {                                                                 \
    _Pragma("unroll") for (int nf = 0; nf < 2; nf++) {                 \
      dst[nf][0] = *(const s16x8*)&sB[buf][h][brow[nf] + sw0];         \
      dst[nf][1] = *(const s16x8*)&sB[buf][h][brow[nf] + sw1];         \
    }                                                                  \
  } while (0)
#define MFMAQ(MG, NG, BB)                                              \
  do {                                                                 \
    _Pragma("unroll") for (int mf = 0; mf < 4; mf++)                   \
    _Pragma("unroll") for (int nf = 0; nf < 2; nf++)                   \
    _Pragma("unroll") for (int ks = 0; ks < 2; ks++)                   \
      acc[MG][NG][mf][nf] = __builtin_amdgcn_mfma_f32_16x16x32_bf16(   \
          a[mf][ks], BB[nf][ks], acc[MG][NG][mf][nf], 0, 0, 0);        \
  } while (0)

  constexpr int NS = KDIM / 64;
  STAGE_T(0, 0);
  WAITV(0);
  SBAR();
  int cur = 0;
  for (int t = 0; t < NS; ++t) {
    const bool more = (t + 1 < NS);
    if (more) STAGE_T(cur ^ 1, t + 1);   // 6-8 loads issued FIRST (T14 spirit)
    __builtin_amdgcn_s_setprio(1);
    LDA(cur, 0);
    LDB(b0, cur, 0);
    MFMAQ(0, 0, b0);
    if (NBH == 2) {
      LDB(b1, cur, 1);
      MFMAQ(0, 1, b1);
    }
    LDA(cur, 1);
    if (NBH == 2) MFMAQ(1, 1, b1);
    MFMAQ(1, 0, b0);
    __builtin_amdgcn_s_setprio(0);
    if (more) {
      WAITV(0);   // stage loads issued ~1000 cyc ago — mostly drained
      SBAR();     // also: all reads of cur done -> next iter may overwrite
      cur ^= 1;
    }
  }
#undef LDA
#undef LDB
#undef MFMAQ
#undef STAGE_T

  // epilogue
  float bv[NBH][2];
#pragma unroll
  for (int ng = 0; ng < NBH; ng++)
#pragma unroll
    for (int nf = 0; nf < 2; nf++)
      bv[ng][nf] = bias[(size_t)e * N + n0 + ng * 128 + wc * 32 + nf * 16 + rsel];
#pragma unroll
  for (int mg = 0; mg < 2; mg++) {
#pragma unroll
    for (int mf = 0; mf < 4; mf++) {
#pragma unroll
      for (int r = 0; r < 4; r++) {
        const int grow = m0 + mg * 128 + wr * 64 + mf * 16 + lhi * 4 + r;
        if (grow < mlimit) {
          if constexpr (EPI == 0) {
            ushort* hrow = Hout + (size_t)grow * N + n0;
#pragma unroll
            for (int ng = 0; ng < NBH; ng++)
#pragma unroll
              for (int nf = 0; nf < 2; nf++) {
                float v = acc[mg][ng][mf][nf][r] + bv[ng][nf];
                hrow[ng * 128 + wc * 32 + nf * 16 + rsel] = f2bf(fmaxf(v, 0.0f));
              }
          } else {
            if (part == 0) {
              const int tok = perm[grow];
              const float sc = pmaxArr[tok];
              float* yrow = Y + (size_t)tok * N + n0;
#pragma unroll
              for (int ng = 0; ng < NBH; ng++)
#pragma unroll
                for (int nf = 0; nf < 2; nf++)
                  yrow[ng * 128 + wc * 32 + nf * 16 + rsel] =
                      (acc[mg][ng][mf][nf][r] + bv[ng][nf]) * sc;
            } else {
              ushort* prow = P1 + (size_t)grow * N + n0;
#pragma unroll
              for (int ng = 0; ng < NBH; ng++)
#pragma unroll
                for (int nf = 0; nf < 2; nf++)
                  prow[ng * 128 + wc * 32 + nf * 16 + rsel] =
                      f2bf(acc[mg][ng][mf][nf][r]);
            }
          }
        }
      }
    }
  }
}

// ---------------- combine: out[perm[slot]] += pmax * P1[slot] ----------------
__global__ __launch_bounds__(256) void combine_kernel(
    const ushort* __restrict__ P1, const int* __restrict__ perm,
    const float* __restrict__ pmaxArr, float* __restrict__ out) {
  const int lane = threadIdx.x & 63;
  const int slot = (blockIdx.x * blockDim.x + threadIdx.x) >> 6;
  if (slot >= NT) return;
  const int tok = perm[slot];
  const float sc = pmaxArr[tok];
  const ushort* src = P1 + (size_t)slot * DOUT;
  float* dst = out + (size_t)tok * DOUT;
#pragma unroll
  for (int half = 0; half < 2; half++) {
    const int i = half * 512 + lane * 8;
    const s16x8 p = *(const s16x8*)(src + i);
    float4 o0 = *(const float4*)(dst + i);
    float4 o1 = *(const float4*)(dst + i + 4);
    o0.x += sc * bf2f((ushort)p[0]); o0.y += sc * bf2f((ushort)p[1]);
    o0.z += sc * bf2f((ushort)p[2]); o0.w += sc * bf2f((ushort)p[3]);
    o1.x += sc * bf2f((ushort)p[4]); o1.y += sc * bf2f((ushort)p[5]);
    o1.z += sc * bf2f((ushort)p[6]); o1.w += sc * bf2f((ushort)p[7]);
    *(float4*)(dst + i) = o0;
    *(float4*)(dst + i + 4) = o1;
  }
}

// ---------------------------------------------------------------------------
extern "C" void kernel_launch(void* const* d_in, const int* in_sizes, int n_in,
                              void* d_out, int out_size, void* d_ws, size_t ws_size,
                              hipStream_t stream) {
  const float* x  = (const float*)d_in[0];
  const float* sw = (const float*)d_in[1];
  const float* sb = (const float*)d_in[2];
  const float* w1 = (const float*)d_in[3];
  const float* b1 = (const float*)d_in[4];
  const float* w2 = (const float*)d_in[5];
  const float* b2 = (const float*)d_in[6];
  float* out = (float*)d_out;
  float* auxp = out + (size_t)NT * DOUT;

  char* wsb = (char*)d_ws;
  int*   cnt      = (int*)wsb;               // 8 ints
  float* probsum  = (float*)(wsb + 32);      // 8 floats
  int*   offsets  = (int*)(wsb + 64);        // 9 ints
  int*   routes   = (int*)(wsb + 256);
  int*   posArr   = routes + NT;
  float* pmaxArr  = (float*)(posArr + NT);
  int*   perm     = (int*)(pmaxArr + NT);
  ushort* Xg = (ushort*)(wsb + 256 + (size_t)4 * 4 * NT);           // [NT+256][DIN]
  ushort* Hg = Xg + (size_t)(NT + 256) * DIN;                       // [NT+256][DFF]
  ushort* Wt = Hg + (size_t)(NT + 256) * DFF;                       // E*DFF*DIN bf16, reused
  size_t needed = (size_t)((char*)Wt - wsb) + (size_t)NEXP * DFF * DIN * 2;
  if (ws_size < needed) return;  // insufficient scratch; fail validation visibly
  ushort* P1 = Xg;  // GEMM2 part1 partial ([NT][DOUT] bf16) — Xg is dead by then

  hipMemsetAsync(d_ws, 0, 64, stream);  // cnt + probsum

  router_kernel<<<NT / 64, 256, 0, stream>>>(x, sw, sb, routes, posArr, pmaxArr, cnt, probsum);
  offsets_aux_kernel<<<1, 64, 0, stream>>>(cnt, probsum, offsets, auxp);
  gather_kernel<<<NT / 4, 256, 0, stream>>>(x, routes, posArr, offsets, perm, Xg);

  // w1: [E][DIN][DFF] -> Wt [E][DFF][DIN]
  transpose_cvt_kernel<<<NEXP * (DIN / 64) * (DFF / 64), 256, 0, stream>>>(w1, Wt, DIN, DFF);
  // GEMM1: 256x256, flat grid 1024 = 8e x 16bx x 8by, expert->XCD swizzle.
  moe_gemm2p_kernel<DIN, 0, 2><<<1024, 512, 0, stream>>>(
      Xg, Wt, b1, offsets, Hg, nullptr, nullptr, nullptr, nullptr, DFF, DIN);

  // w2: [E][DFF][DOUT] -> Wt [E][DOUT][DFF]  (reuse Wt; stream-ordered)
  transpose_cvt_kernel<<<NEXP * (DFF / 64) * (DOUT / 64), 256, 0, stream>>>(w2, Wt, DFF, DOUT);
  // GEMM2: 256x128 tiles, split-K=2 (z = part*8+e, each block K=2048).
  // live ~ 8bx * ~4.25my * 16z = ~544 blocks -> ~2.1 even rounds, fine grains.
  moe_gemm2p_kernel<DFF / 2, 3, 1><<<dim3(DOUT / 128, 10, 16), 512, 0, stream>>>(
      Hg, Wt, b2, offsets, nullptr, out, P1, perm, pmaxArr, DOUT, DFF);
  combine_kernel<<<NT / 4, 256, 0, stream>>>(P1, perm, pmaxArr, out);
}

// Round 10
// 393.364 us; speedup vs baseline: 1.1290x; 1.1290x over previous
//
#include <hip/hip_runtime.h>
#include <cstdint>
#include <cstddef>

#define NT   8192
#define DIN  1024
#define DFF  4096
#define DOUT 1024
#define NEXP 8

typedef float  f32x4v __attribute__((ext_vector_type(4)));
typedef short  s16x8  __attribute__((ext_vector_type(8)));
typedef short  s16x4  __attribute__((ext_vector_type(4)));

__device__ __forceinline__ ushort f2bf(float f) {
  union { float f; uint32_t u; } c; c.f = f;
  uint32_t u = c.u;
  return (ushort)((u + 0x7fffu + ((u >> 16) & 1u)) >> 16);  // RNE
}

// ---------------- router: 1 block = 64 tokens, block-level atomic reduction --
__global__ __launch_bounds__(256) void router_kernel(
    const float* __restrict__ x, const float* __restrict__ sw,
    const float* __restrict__ sb,
    int* __restrict__ routes, int* __restrict__ posArr,
    float* __restrict__ pmaxArr,
    int* __restrict__ cnt, float* __restrict__ probsum) {
  __shared__ int   sRoute[64];
  __shared__ float sProb[4][NEXP];
  __shared__ int   sBase[NEXP];

  const int lane = threadIdx.x & 63;
  const int w    = threadIdx.x >> 6;
  const int t0   = blockIdx.x * 64;

  float bias[NEXP];
#pragma unroll
  for (int e = 0; e < NEXP; e++) bias[e] = sb[e];

  float wprob[NEXP];
#pragma unroll
  for (int e = 0; e < NEXP; e++) wprob[e] = 0.0f;

  for (int k = 0; k < 16; k++) {
    const int t = t0 + w * 16 + k;
    const float* xr = x + (size_t)t * DIN;
    float acc[NEXP];
#pragma unroll
    for (int e = 0; e < NEXP; e++) acc[e] = 0.0f;
#pragma unroll
    for (int it = 0; it < DIN / 64; it++) {
      const int i = it * 64 + lane;
      const float xv = xr[i];
      const float4 s0 = *(const float4*)(sw + (size_t)i * NEXP);
      const float4 s1 = *(const float4*)(sw + (size_t)i * NEXP + 4);
      acc[0] += xv * s0.x; acc[1] += xv * s0.y; acc[2] += xv * s0.z; acc[3] += xv * s0.w;
      acc[4] += xv * s1.x; acc[5] += xv * s1.y; acc[6] += xv * s1.z; acc[7] += xv * s1.w;
    }
#pragma unroll
    for (int e = 0; e < NEXP; e++) {
#pragma unroll
      for (int off = 32; off > 0; off >>= 1) acc[e] += __shfl_xor(acc[e], off, 64);
    }
    float m = acc[0] + bias[0]; int am = 0;
    float lg[NEXP];
#pragma unroll
    for (int e = 0; e < NEXP; e++) {
      lg[e] = acc[e] + bias[e];
      if (lg[e] > m) { m = lg[e]; am = e; }
    }
    float esum = 0.0f;
    float pe[NEXP];
#pragma unroll
    for (int e = 0; e < NEXP; e++) { pe[e] = __expf(lg[e] - m); esum += pe[e]; }
    const float inv = 1.0f / esum;
#pragma unroll
    for (int e = 0; e < NEXP; e++) wprob[e] += pe[e] * inv;
    if (lane == 0) {
      routes[t] = am;
      pmaxArr[t] = inv;           // pe[am] == 1 -> pmax = 1/esum
      sRoute[w * 16 + k] = am;
    }
  }
  if (lane == 0) {
#pragma unroll
    for (int e = 0; e < NEXP; e++) sProb[w][e] = wprob[e];
  }
  __syncthreads();

  const int tid = threadIdx.x;
  if (tid < NEXP) {
    float s = sProb[0][tid] + sProb[1][tid] + sProb[2][tid] + sProb[3][tid];
    atomicAdd(&probsum[tid], s);
    int c = 0;
#pragma unroll
    for (int j = 0; j < 64; j++) c += (sRoute[j] == tid);
    sBase[tid] = atomicAdd(&cnt[tid], c);
  }
  __syncthreads();

  if (tid < 64) {
    const int r = sRoute[tid];
    int rank = 0;
    for (int j = 0; j < 64; j++) rank += (j < tid) & (sRoute[j] == r);
    posArr[t0 + tid] = sBase[r] + rank;
  }
}

// ---------------- offsets (exclusive scan of 8) + aux loss -------------------
__global__ void offsets_aux_kernel(const int* __restrict__ cnt, const float* __restrict__ probsum,
                                   int* __restrict__ offsets, float* __restrict__ auxout) {
  if (threadIdx.x == 0) {
    int o = 0; float aux = 0.0f;
    for (int e = 0; e < NEXP; e++) {
      offsets[e] = o; o += cnt[e];
      aux += (float)cnt[e] * probsum[e];
    }
    offsets[NEXP] = o;
    auxout[0] = aux * ((float)NEXP / (float)NT);
  }
}

// ---------------- gather tokens into expert-contiguous bf16 rows -------------
__global__ void gather_kernel(const float* __restrict__ x, const int* __restrict__ routes,
                              const int* __restrict__ posArr, const int* __restrict__ offsets,
                              int* __restrict__ perm, ushort* __restrict__ Xg) {
  const int lane = threadIdx.x & 63;
  const int t = (blockIdx.x * blockDim.x + threadIdx.x) >> 6;
  if (t >= NT) return;
  const int slot = offsets[routes[t]] + posArr[t];
  if (lane == 0) perm[slot] = t;
  const float* src = x + (size_t)t * DIN;
  ushort* dst = Xg + (size_t)slot * DIN;
#pragma unroll
  for (int half = 0; half < 2; half++) {
    int i = half * 512 + lane * 8;
    float4 v0 = *(const float4*)(src + i);
    float4 v1 = *(const float4*)(src + i + 4);
    s16x8 p;
    p[0] = (short)f2bf(v0.x); p[1] = (short)f2bf(v0.y);
    p[2] = (short)f2bf(v0.z); p[3] = (short)f2bf(v0.w);
    p[4] = (short)f2bf(v1.x); p[5] = (short)f2bf(v1.y);
    p[6] = (short)f2bf(v1.z); p[7] = (short)f2bf(v1.w);
    *(s16x8*)(dst + i) = p;
  }
}

// ---------------- transpose + fp32->bf16: [E][K][N] -> [E][N][K] -------------
__global__ void transpose_cvt_kernel(const float* __restrict__ src, ushort* __restrict__ dst,
                                     const int K, const int N) {
  __shared__ float tile[64][65];
  const int ntn = N >> 6;
  const int ntk = K >> 6;
  int b = blockIdx.x;
  const int tn = b % ntn; b /= ntn;
  const int tk = b % ntk; const int e = b / ntk;
  const float* s = src + ((size_t)e * K + (size_t)tk * 64) * N + (size_t)tn * 64;
  const int c4 = (threadIdx.x & 15) * 4;
  const int r0 = threadIdx.x >> 4;  // 0..15
#pragma unroll
  for (int p = 0; p < 4; p++) {
    const int row = r0 + p * 16;
    float4 v = *(const float4*)(s + (size_t)row * N + c4);
    tile[row][c4 + 0] = v.x; tile[row][c4 + 1] = v.y;
    tile[row][c4 + 2] = v.z; tile[row][c4 + 3] = v.w;
  }
  __syncthreads();
  ushort* d = dst + ((size_t)e * N + (size_t)tn * 64) * K + (size_t)tk * 64;
#pragma unroll
  for (int p = 0; p < 4; p++) {
    const int nrow = r0 + p * 16;
    s16x4 o;
    o[0] = (short)f2bf(tile[c4 + 0][nrow]);
    o[1] = (short)f2bf(tile[c4 + 1][nrow]);
    o[2] = (short)f2bf(tile[c4 + 2][nrow]);
    o[3] = (short)f2bf(tile[c4 + 3][nrow]);
    *(s16x4*)(d + (size_t)nrow * K + c4) = o;
  }
}

#define GLD16(g, l)                                                                        \
  __builtin_amdgcn_global_load_lds((const __attribute__((address_space(1))) uint32_t*)(g), \
                                   (__attribute__((address_space(3))) uint32_t*)(l), 16, 0, 0)

#define SBAR()   asm volatile("s_barrier" ::: "memory")
#define WAITV(n) asm volatile("s_waitcnt vmcnt(" #n ")" ::: "memory")

// ====== 256x256 / BK=64 / 8-wave FIXED-HALF geometry / m201-style 4-phase ====
// Wave (wr=wid>>2, wc=wid&3) owns CONTIGUOUS output 128x64: rows wr*128+.. ,
// cols wc*64+.. -> reads ONLY A-half wr and B-half (wc>>1) (m201 geometry).
// LDS: ring of 4 half-tile slots per operand; tile t half h -> slot (2t+h)&3.
// Per K-tile 4 phases, each {ds_read subtile ; stage ; barrier ; setprio +
// 16 MFMA ; barrier}:
//   P1: read a(mf0-3)+b(nf0-1) [12]   P2: read b(nf2-3) [4]
//   P3: read a(mf4-7) [8], stage B(t+2,0),B(t+2,1)  (B(t) reads retired @P2bar2)
//   P4: stage A(t+2,0),A(t+2,1)       (A(t) reads retired @P3bar2)
//   single counted WAITV(8) at P4 end: 8 newest in flight = tile t+2's ->
//   guarantees tile t+1 (staged during t-1, 4-5 phases ago) fully landed.
// Swizzle: (row,kslot16B) at phys kslot^(row&7) via pre-swizzled global src +
// linear LDS dest (rule #21); 0 bank conflicts (verified R3+).
// EPI==0: flat grid + expert->XCD chunk swizzle (FETCH 200->52MB, R8) -> Hout.
// EPI==1: dim3 grid -> Y fp32 scatter with bias+pmax.
// NOTE: launch_bounds min-waves/EU MUST be 1 (",2" caps 128 VGPR -> acc spill).
template <int KDIM, int EPI>
__global__ __launch_bounds__(512, 1) void moe_gemm8p_kernel(
    const ushort* __restrict__ A,   // [slots][KDIM] bf16 expert-contiguous
    const ushort* __restrict__ BT,  // [E][N][KDIM] bf16
    const float* __restrict__ bias, // [E][N]
    const int* __restrict__ offsets,
    ushort* __restrict__ Hout,      // EPI==0: [slots][N] bf16 (relu)
    float* __restrict__ Y,          // EPI==1: [NT][N] fp32 scatter
    const int* __restrict__ perm, const float* __restrict__ pmaxArr,
    const int N) {
  __shared__ ushort sA4[4][8192];
  __shared__ ushort sB4[4][8192];
  int e, bx, by;
  if constexpr (EPI == 0) {
    const int logical = ((blockIdx.x & 7) << 7) + (blockIdx.x >> 3);
    e = logical >> 7;
    bx = (logical & 127) >> 3;
    by = logical & 7;
  } else {
    bx = blockIdx.x; by = blockIdx.y; e = blockIdx.z;
  }
  const int mlimit = offsets[e + 1];
  const int m0 = offsets[e] + by * 256;
  if (m0 >= mlimit) return;
  const int n0 = bx * 256;
  const int tid = threadIdx.x;
  const int lane = tid & 63;
  const int wid = tid >> 6;
  const int wr = wid >> 2;   // 0..1 : wave's A-half (rows wr*128..+127)
  const int wc = wid & 3;    // 0..3 : wave's 64-col group; B-half = wc>>1
  const int hb = wc >> 1;
  const int rsel = lane & 15;
  const int lhi = lane >> 4; // 0..3

  // staging: thread covers bytes tid*16 (+8192B) of each 16KB half-tile.
  const int srow = wid * 8 + (lane >> 3);           // local row, chunk 0
  const int scol = ((lane & 7) ^ (lane >> 3)) * 8;  // pre-swizzled source col
  const ushort* gA = A + (size_t)(m0 + srow) * KDIM + scol;
  const ushort* gB = BT + ((size_t)e * N + n0 + srow) * KDIM + scol;
  const int ldst = tid * 8;  // elem offset; +4096 elems for rows +64
  const size_t LK = (size_t)KDIM;

#define STAGE_A(s, h, kt)                                              \
  do {                                                                 \
    const ushort* g_ = gA + (size_t)((h) * 128) * LK + (size_t)(kt) * 64; \
    GLD16(g_, &sA4[s][ldst]);                                          \
    GLD16(g_ + 64 * LK, &sA4[s][ldst + 4096]);                         \
  } while (0)
#define STAGE_B(s, h, kt)                                              \
  do {                                                                 \
    const ushort* g_ = gB + (size_t)((h) * 128) * LK + (size_t)(kt) * 64; \
    GLD16(g_, &sB4[s][ldst]);                                          \
    GLD16(g_ + 64 * LK, &sB4[s][ldst + 4096]);                         \
  } while (0)

  f32x4v acc[2][4][4];   // [mg][mf][nf]
#pragma unroll
  for (int g = 0; g < 2; g++)
#pragma unroll
    for (int mf = 0; mf < 4; mf++)
#pragma unroll
      for (int nf = 0; nf < 4; nf++) acc[g][mf][nf] = (f32x4v)0.0f;

  const int rsw = rsel & 7;
  const int sw0 = ((lhi) ^ rsw) * 8;       // phys 16B-slot, k-step 0
  const int sw1 = ((4 + lhi) ^ rsw) * 8;   // phys 16B-slot, k-step 1
  const int arow0 = rsel * 64;                         // + mf*1024 (+4096 for mg1)
  const int brow0 = ((wc & 1) * 64 + rsel) * 64;       // + nf*1024

  s16x8 a[4][2], b0[2][2], b1[2][2];

#define LDA03(slot)                                                    \
  do {                                                                 \
    _Pragma("unroll") for (int mf = 0; mf < 4; mf++) {                 \
      a[mf][0] = *(const s16x8*)&sA4[slot][arow0 + mf * 1024 + sw0];   \
      a[mf][1] = *(const s16x8*)&sA4[slot][arow0 + mf * 1024 + sw1];   \
    }                                                                  \
  } while (0)
#define LDA47(slot)                                                    \
  do {                                                                 \
    _Pragma("unroll") for (int mf = 0; mf < 4; mf++) {                 \
      a[mf][0] = *(const s16x8*)&sA4[slot][arow0 + 4096 + mf * 1024 + sw0]; \
      a[mf][1] = *(const s16x8*)&sA4[slot][arow0 + 4096 + mf * 1024 + sw1]; \
    }                                                                  \
  } while (0)
#define LDB2(dst, slot, nfb)                                           \
  do {                                                                 \
    _Pragma("unroll") for (int nf = 0; nf < 2; nf++) {                 \
      dst[nf][0] = *(const s16x8*)&sB4[slot][brow0 + ((nfb) + nf) * 1024 + sw0]; \
      dst[nf][1] = *(const s16x8*)&sB4[slot][brow0 + ((nfb) + nf) * 1024 + sw1]; \
    }                                                                  \
  } while (0)
#define MFMAPH(MG, BB, NFB)                                            \
  do {                                                                 \
    __builtin_amdgcn_s_setprio(1);                                     \
    _Pragma("unroll") for (int mf = 0; mf < 4; mf++)                   \
    _Pragma("unroll") for (int nf = 0; nf < 2; nf++)                   \
    _Pragma("unroll") for (int ks = 0; ks < 2; ks++)                   \
      acc[MG][mf][(NFB) + nf] = __builtin_amdgcn_mfma_f32_16x16x32_bf16( \
          a[mf][ks], BB[nf][ks], acc[MG][mf][(NFB) + nf], 0, 0, 0);    \
    __builtin_amdgcn_s_setprio(0);                                     \
  } while (0)

  constexpr int NS = KDIM / 64;
  // prologue: tiles 0 and 1 fully staged (16 ops); vmcnt(8) -> tile0 landed.
  STAGE_A(0, 0, 0); STAGE_A(1, 1, 0); STAGE_B(0, 0, 0); STAGE_B(1, 1, 0);
  STAGE_B(2, 0, 1); STAGE_B(3, 1, 1); STAGE_A(2, 0, 1); STAGE_A(3, 1, 1);
  WAITV(8);
  SBAR();

#pragma unroll 2
  for (int t = 0; t < NS; ++t) {
    const int sa = (2 * t + wr) & 3;   // wave's A slot this tile
    const int sb = (2 * t + hb) & 3;   // wave's B slot this tile
    const int r0s = (2 * t) & 3, r1s = (2 * t + 1) & 3;  // restage slots (t+2)
    const bool st2 = (t + 2 < NS);
    // P1: a(mf0-3) + b(nf0-1)
    LDA03(sa);
    LDB2(b0, sb, 0);
    SBAR();
    MFMAPH(0, b0, 0);
    SBAR();
    // P2: b(nf2-3)
    LDB2(b1, sb, 2);
    SBAR();
    MFMAPH(0, b1, 2);
    SBAR();
    // P3: a(mf4-7); stage B(t+2) both halves (B(t) reads retired @P2 bar2)
    LDA47(sa);
    if (st2) { STAGE_B(r0s, 0, t + 2); STAGE_B(r1s, 1, t + 2); }
    SBAR();
    MFMAPH(1, b1, 2);
    SBAR();
    // P4: no reads; stage A(t+2) both halves (A(t) reads retired @P3 bar2)
    if (st2) { STAGE_A(r0s, 0, t + 2); STAGE_A(r1s, 1, t + 2); }
    SBAR();
    MFMAPH(1, b0, 0);
    if (st2) { WAITV(8); } else { WAITV(0); }  // tile t+1 fully landed
    SBAR();
  }
#undef LDA03
#undef LDA47
#undef LDB2
#undef MFMAPH
#undef STAGE_A
#undef STAGE_B

  // epilogue: wave's contiguous 128x64 at (m0 + wr*128, n0 + wc*64)
  float bv[4];
#pragma unroll
  for (int nf = 0; nf < 4; nf++)
    bv[nf] = bias[(size_t)e * N + n0 + wc * 64 + nf * 16 + rsel];
#pragma unroll
  for (int mg = 0; mg < 2; mg++) {
#pragma unroll
    for (int mf = 0; mf < 4; mf++) {
#pragma unroll
      for (int r = 0; r < 4; r++) {
        const int grow = m0 + wr * 128 + mg * 64 + mf * 16 + lhi * 4 + r;
        if (grow < mlimit) {
          if constexpr (EPI == 0) {
            ushort* hrow = Hout + (size_t)grow * N + n0 + wc * 64;
#pragma unroll
            for (int nf = 0; nf < 4; nf++) {
              float v = acc[mg][mf][nf][r] + bv[nf];
              hrow[nf * 16 + rsel] = f2bf(fmaxf(v, 0.0f));
            }
          } else {
            const int tok = perm[grow];
            const float sc = pmaxArr[tok];
            float* yrow = Y + (size_t)tok * N + n0 + wc * 64;
#pragma unroll
            for (int nf = 0; nf < 4; nf++)
              yrow[nf * 16 + rsel] = (acc[mg][mf][nf][r] + bv[nf]) * sc;
          }
        }
      }
    }
  }
}

// ---------------------------------------------------------------------------
extern "C" void kernel_launch(void* const* d_in, const int* in_sizes, int n_in,
                              void* d_out, int out_size, void* d_ws, size_t ws_size,
                              hipStream_t stream) {
  const float* x  = (const float*)d_in[0];
  const float* sw = (const float*)d_in[1];
  const float* sb = (const float*)d_in[2];
  const float* w1 = (const float*)d_in[3];
  const float* b1 = (const float*)d_in[4];
  const float* w2 = (const float*)d_in[5];
  const float* b2 = (const float*)d_in[6];
  float* out = (float*)d_out;
  float* auxp = out + (size_t)NT * DOUT;

  char* wsb = (char*)d_ws;
  int*   cnt      = (int*)wsb;               // 8 ints
  float* probsum  = (float*)(wsb + 32);      // 8 floats
  int*   offsets  = (int*)(wsb + 64);        // 9 ints
  int*   routes   = (int*)(wsb + 256);
  int*   posArr   = routes + NT;
  float* pmaxArr  = (float*)(posArr + NT);
  int*   perm     = (int*)(pmaxArr + NT);
  ushort* Xg = (ushort*)(wsb + 256 + (size_t)4 * 4 * NT);           // [NT+256][DIN]
  ushort* Hg = Xg + (size_t)(NT + 256) * DIN;                       // [NT+256][DFF]
  ushort* Wt = Hg + (size_t)(NT + 256) * DFF;                       // E*DFF*DIN bf16, reused
  size_t needed = (size_t)((char*)Wt - wsb) + (size_t)NEXP * DFF * DIN * 2;
  if (ws_size < needed) return;  // insufficient scratch; fail validation visibly

  hipMemsetAsync(d_ws, 0, 64, stream);  // cnt + probsum

  router_kernel<<<NT / 64, 256, 0, stream>>>(x, sw, sb, routes, posArr, pmaxArr, cnt, probsum);
  offsets_aux_kernel<<<1, 64, 0, stream>>>(cnt, probsum, offsets, auxp);
  gather_kernel<<<NT / 4, 256, 0, stream>>>(x, routes, posArr, offsets, perm, Xg);

  // w1: [E][DIN][DFF] -> Wt [E][DFF][DIN]
  transpose_cvt_kernel<<<NEXP * (DIN / 64) * (DFF / 64), 256, 0, stream>>>(w1, Wt, DIN, DFF);
  // GEMM1: flat grid 1024 = 8e x 16bx x 8by, expert->XCD chunk swizzle.
  moe_gemm8p_kernel<DIN, 0><<<1024, 512, 0, stream>>>(
      Xg, Wt, b1, offsets, Hg, nullptr, nullptr, nullptr, DFF);

  // w2: [E][DFF][DOUT] -> Wt [E][DOUT][DFF]  (reuse Wt; stream-ordered)
  transpose_cvt_kernel<<<NEXP * (DFF / 64) * (DOUT / 64), 256, 0, stream>>>(w2, Wt, DFF, DOUT);
  // GEMM2: direct (no split-K), ~128 live blocks.
  moe_gemm8p_kernel<DFF, 1><<<dim3(DOUT / 256, 8, NEXP), 512, 0, stream>>>(
      Hg, Wt, b2, offsets, nullptr, out, perm, pmaxArr, DOUT);
}

// Round 11
// 357.995 us; speedup vs baseline: 1.2405x; 1.0988x over previous
//
#include <hip/hip_runtime.h>
#include <cstdint>
#include <cstddef>

#define NT   8192
#define DIN  1024
#define DFF  4096
#define DOUT 1024
#define NEXP 8

typedef float  f32x4v __attribute__((ext_vector_type(4)));
typedef short  s16x8  __attribute__((ext_vector_type(8)));
typedef short  s16x4  __attribute__((ext_vector_type(4)));

__device__ __forceinline__ ushort f2bf(float f) {
  union { float f; uint32_t u; } c; c.f = f;
  uint32_t u = c.u;
  return (ushort)((u + 0x7fffu + ((u >> 16) & 1u)) >> 16);  // RNE
}

// ---------------- router: 1 block = 64 tokens, block-level atomic reduction --
__global__ __launch_bounds__(256) void router_kernel(
    const float* __restrict__ x, const float* __restrict__ sw,
    const float* __restrict__ sb,
    int* __restrict__ routes, int* __restrict__ posArr,
    float* __restrict__ pmaxArr,
    int* __restrict__ cnt, float* __restrict__ probsum) {
  __shared__ int   sRoute[64];
  __shared__ float sProb[4][NEXP];
  __shared__ int   sBase[NEXP];

  const int lane = threadIdx.x & 63;
  const int w    = threadIdx.x >> 6;
  const int t0   = blockIdx.x * 64;

  float bias[NEXP];
#pragma unroll
  for (int e = 0; e < NEXP; e++) bias[e] = sb[e];

  float wprob[NEXP];
#pragma unroll
  for (int e = 0; e < NEXP; e++) wprob[e] = 0.0f;

  for (int k = 0; k < 16; k++) {
    const int t = t0 + w * 16 + k;
    const float* xr = x + (size_t)t * DIN;
    float acc[NEXP];
#pragma unroll
    for (int e = 0; e < NEXP; e++) acc[e] = 0.0f;
#pragma unroll
    for (int it = 0; it < DIN / 64; it++) {
      const int i = it * 64 + lane;
      const float xv = xr[i];
      const float4 s0 = *(const float4*)(sw + (size_t)i * NEXP);
      const float4 s1 = *(const float4*)(sw + (size_t)i * NEXP + 4);
      acc[0] += xv * s0.x; acc[1] += xv * s0.y; acc[2] += xv * s0.z; acc[3] += xv * s0.w;
      acc[4] += xv * s1.x; acc[5] += xv * s1.y; acc[6] += xv * s1.z; acc[7] += xv * s1.w;
    }
#pragma unroll
    for (int e = 0; e < NEXP; e++) {
#pragma unroll
      for (int off = 32; off > 0; off >>= 1) acc[e] += __shfl_xor(acc[e], off, 64);
    }
    float m = acc[0] + bias[0]; int am = 0;
    float lg[NEXP];
#pragma unroll
    for (int e = 0; e < NEXP; e++) {
      lg[e] = acc[e] + bias[e];
      if (lg[e] > m) { m = lg[e]; am = e; }
    }
    float esum = 0.0f;
    float pe[NEXP];
#pragma unroll
    for (int e = 0; e < NEXP; e++) { pe[e] = __expf(lg[e] - m); esum += pe[e]; }
    const float inv = 1.0f / esum;
#pragma unroll
    for (int e = 0; e < NEXP; e++) wprob[e] += pe[e] * inv;
    if (lane == 0) {
      routes[t] = am;
      pmaxArr[t] = inv;           // pe[am] == 1 -> pmax = 1/esum
      sRoute[w * 16 + k] = am;
    }
  }
  if (lane == 0) {
#pragma unroll
    for (int e = 0; e < NEXP; e++) sProb[w][e] = wprob[e];
  }
  __syncthreads();

  const int tid = threadIdx.x;
  if (tid < NEXP) {
    float s = sProb[0][tid] + sProb[1][tid] + sProb[2][tid] + sProb[3][tid];
    atomicAdd(&probsum[tid], s);
    int c = 0;
#pragma unroll
    for (int j = 0; j < 64; j++) c += (sRoute[j] == tid);
    sBase[tid] = atomicAdd(&cnt[tid], c);
  }
  __syncthreads();

  if (tid < 64) {
    const int r = sRoute[tid];
    int rank = 0;
    for (int j = 0; j < 64; j++) rank += (j < tid) & (sRoute[j] == r);
    posArr[t0 + tid] = sBase[r] + rank;
  }
}

// ---------------- offsets (exclusive scan of 8) + aux loss -------------------
__global__ void offsets_aux_kernel(const int* __restrict__ cnt, const float* __restrict__ probsum,
                                   int* __restrict__ offsets, float* __restrict__ auxout) {
  if (threadIdx.x == 0) {
    int o = 0; float aux = 0.0f;
    for (int e = 0; e < NEXP; e++) {
      offsets[e] = o; o += cnt[e];
      aux += (float)cnt[e] * probsum[e];
    }
    offsets[NEXP] = o;
    auxout[0] = aux * ((float)NEXP / (float)NT);
  }
}

// ---------------- gather tokens into expert-contiguous bf16 rows -------------
__global__ void gather_kernel(const float* __restrict__ x, const int* __restrict__ routes,
                              const int* __restrict__ posArr, const int* __restrict__ offsets,
                              int* __restrict__ perm, ushort* __restrict__ Xg) {
  const int lane = threadIdx.x & 63;
  const int t = (blockIdx.x * blockDim.x + threadIdx.x) >> 6;
  if (t >= NT) return;
  const int slot = offsets[routes[t]] + posArr[t];
  if (lane == 0) perm[slot] = t;
  const float* src = x + (size_t)t * DIN;
  ushort* dst = Xg + (size_t)slot * DIN;
#pragma unroll
  for (int half = 0; half < 2; half++) {
    int i = half * 512 + lane * 8;
    float4 v0 = *(const float4*)(src + i);
    float4 v1 = *(const float4*)(src + i + 4);
    s16x8 p;
    p[0] = (short)f2bf(v0.x); p[1] = (short)f2bf(v0.y);
    p[2] = (short)f2bf(v0.z); p[3] = (short)f2bf(v0.w);
    p[4] = (short)f2bf(v1.x); p[5] = (short)f2bf(v1.y);
    p[6] = (short)f2bf(v1.z); p[7] = (short)f2bf(v1.w);
    *(s16x8*)(dst + i) = p;
  }
}

// ---------------- transpose + fp32->bf16: [E][K][N] -> [E][N][K] -------------
__global__ void transpose_cvt_kernel(const float* __restrict__ src, ushort* __restrict__ dst,
                                     const int K, const int N) {
  __shared__ float tile[64][65];
  const int ntn = N >> 6;
  const int ntk = K >> 6;
  int b = blockIdx.x;
  const int tn = b % ntn; b /= ntn;
  const int tk = b % ntk; const int e = b / ntk;
  const float* s = src + ((size_t)e * K + (size_t)tk * 64) * N + (size_t)tn * 64;
  const int c4 = (threadIdx.x & 15) * 4;
  const int r0 = threadIdx.x >> 4;  // 0..15
#pragma unroll
  for (int p = 0; p < 4; p++) {
    const int row = r0 + p * 16;
    float4 v = *(const float4*)(s + (size_t)row * N + c4);
    tile[row][c4 + 0] = v.x; tile[row][c4 + 1] = v.y;
    tile[row][c4 + 2] = v.z; tile[row][c4 + 3] = v.w;
  }
  __syncthreads();
  ushort* d = dst + ((size_t)e * N + (size_t)tn * 64) * K + (size_t)tk * 64;
#pragma unroll
  for (int p = 0; p < 4; p++) {
    const int nrow = r0 + p * 16;
    s16x4 o;
    o[0] = (short)f2bf(tile[c4 + 0][nrow]);
    o[1] = (short)f2bf(tile[c4 + 1][nrow]);
    o[2] = (short)f2bf(tile[c4 + 2][nrow]);
    o[3] = (short)f2bf(tile[c4 + 3][nrow]);
    *(s16x4*)(d + (size_t)nrow * K + c4) = o;
  }
}

#define GLD16(g, l)                                                                        \
  __builtin_amdgcn_global_load_lds((const __attribute__((address_space(1))) uint32_t*)(g), \
                                   (__attribute__((address_space(3))) uint32_t*)(l), 16, 0, 0)

#define SBAR()   asm volatile("s_barrier" ::: "memory")
#define WAITV(n) asm volatile("s_waitcnt vmcnt(" #n ")" ::: "memory")
#define LGKM0()  asm volatile("s_waitcnt lgkmcnt(0)" ::: "memory")

// == 256x256 / BK=64 / 8-wave fixed-half / 4-phase SINGLE-BARRIER (m201 core) =
// Wave (wr=wid>>2, wc=wid&3) owns contiguous 128x64 output; reads only A-half
// wr and B-half wc>>1. LDS: ring of 4 half-slots/operand; tile t half h ->
// slot (2t+h)&3.
// Phase = { ds_reads ; stages ; [vmcnt] ; lgkmcnt(0) ; s_barrier ;
//           setprio(1) + 16 MFMA + setprio(0) }   — ONE barrier per phase.
// After its MFMA a wave slips straight into the next phase's ds_reads while
// SIMD-mates still MFMA -> LDS port / MFMA pipe overlap (the m201 mechanism;
// R5-R9's second barrier forced lockstep alternation = 20% MfmaUtil ceiling).
// Reads: P1 = A(mg0)8 + b0 4 + b1 4; P2 = A(mg1)8; P3,P4 = none.
// Stages(t+2): B both halves @P3, A both halves @P4.
// Safety: lgkmcnt(0) BEFORE each barrier => passing barrier_k implies all
// waves' reads<=k complete; B slots last read P1 / restaged P3, A last read
// P2 / restaged P4 (>=2-barrier separation). Landing: counted WAITV(8) at P4
// (8 newest = t+2's stages) => tile t+1 landed before its P1 reads.
// NOTE: launch_bounds min-waves/EU MUST be 1 (",2" caps 128 VGPR -> acc spill).
template <int KDIM, int EPI>
__global__ __launch_bounds__(512, 1) void moe_gemm8p_kernel(
    const ushort* __restrict__ A,   // [slots][KDIM] bf16 expert-contiguous
    const ushort* __restrict__ BT,  // [E][N][KDIM] bf16
    const float* __restrict__ bias, // [E][N]
    const int* __restrict__ offsets,
    ushort* __restrict__ Hout,      // EPI==0: [slots][N] bf16 (relu)
    float* __restrict__ Y,          // EPI==1: [NT][N] fp32 scatter
    const int* __restrict__ perm, const float* __restrict__ pmaxArr,
    const int N) {
  __shared__ ushort sA4[4][8192];
  __shared__ ushort sB4[4][8192];
  int e, bx, by;
  if constexpr (EPI == 0) {
    const int logical = ((blockIdx.x & 7) << 7) + (blockIdx.x >> 3);
    e = logical >> 7;
    bx = (logical & 127) >> 3;
    by = logical & 7;
  } else {
    bx = blockIdx.x; by = blockIdx.y; e = blockIdx.z;
  }
  const int mlimit = offsets[e + 1];
  const int m0 = offsets[e] + by * 256;
  if (m0 >= mlimit) return;
  const int n0 = bx * 256;
  const int tid = threadIdx.x;
  const int lane = tid & 63;
  const int wid = tid >> 6;
  const int wr = wid >> 2;   // 0..1 : wave's A-half (rows wr*128..+127)
  const int wc = wid & 3;    // 0..3 : wave's 64-col group; B-half = wc>>1
  const int hb = wc >> 1;
  const int rsel = lane & 15;
  const int lhi = lane >> 4; // 0..3

  // staging: thread covers bytes tid*16 (+8192B) of each 16KB half-tile.
  const int srow = wid * 8 + (lane >> 3);           // local row, chunk 0
  const int scol = ((lane & 7) ^ (lane >> 3)) * 8;  // pre-swizzled source col
  const ushort* gA = A + (size_t)(m0 + srow) * KDIM + scol;
  const ushort* gB = BT + ((size_t)e * N + n0 + srow) * KDIM + scol;
  const int ldst = tid * 8;  // elem offset; +4096 elems for rows +64
  const size_t LK = (size_t)KDIM;

#define STAGE_A(s, h, kt)                                              \
  do {                                                                 \
    const ushort* g_ = gA + (size_t)((h) * 128) * LK + (size_t)(kt) * 64; \
    GLD16(g_, &sA4[s][ldst]);                                          \
    GLD16(g_ + 64 * LK, &sA4[s][ldst + 4096]);                         \
  } while (0)
#define STAGE_B(s, h, kt)                                              \
  do {                                                                 \
    const ushort* g_ = gB + (size_t)((h) * 128) * LK + (size_t)(kt) * 64; \
    GLD16(g_, &sB4[s][ldst]);                                          \
    GLD16(g_ + 64 * LK, &sB4[s][ldst + 4096]);                         \
  } while (0)

  f32x4v acc[2][4][4];   // [mg][mf][nf]
#pragma unroll
  for (int g = 0; g < 2; g++)
#pragma unroll
    for (int mf = 0; mf < 4; mf++)
#pragma unroll
      for (int nf = 0; nf < 4; nf++) acc[g][mf][nf] = (f32x4v)0.0f;

  const int rsw = rsel & 7;
  const int sw0 = ((lhi) ^ rsw) * 8;       // phys 16B-slot, k-step 0
  const int sw1 = ((4 + lhi) ^ rsw) * 8;   // phys 16B-slot, k-step 1
  const int arow0 = rsel * 64;                         // + mf*1024 (+4096 mg1)
  const int brow0 = ((wc & 1) * 64 + rsel) * 64;       // + nf*1024

  s16x8 a[4][2], b0[2][2], b1[2][2];

#define LDA03(slot)                                                    \
  do {                                                                 \
    _Pragma("unroll") for (int mf = 0; mf < 4; mf++) {                 \
      a[mf][0] = *(const s16x8*)&sA4[slot][arow0 + mf * 1024 + sw0];   \
      a[mf][1] = *(const s16x8*)&sA4[slot][arow0 + mf * 1024 + sw1];   \
    }                                                                  \
  } while (0)
#define LDA47(slot)                                                    \
  do {                                                                 \
    _Pragma("unroll") for (int mf = 0; mf < 4; mf++) {                 \
      a[mf][0] = *(const s16x8*)&sA4[slot][arow0 + 4096 + mf * 1024 + sw0]; \
      a[mf][1] = *(const s16x8*)&sA4[slot][arow0 + 4096 + mf * 1024 + sw1]; \
    }                                                                  \
  } while (0)
#define LDB2(dst, slot, nfb)                                           \
  do {                                                                 \
    _Pragma("unroll") for (int nf = 0; nf < 2; nf++) {                 \
      dst[nf][0] = *(const s16x8*)&sB4[slot][brow0 + ((nfb) + nf) * 1024 + sw0]; \
      dst[nf][1] = *(const s16x8*)&sB4[slot][brow0 + ((nfb) + nf) * 1024 + sw1]; \
    }                                                                  \
  } while (0)
#define MFMAPH(MG, BB, NFB)                                            \
  do {                                                                 \
    __builtin_amdgcn_s_setprio(1);                                     \
    _Pragma("unroll") for (int mf = 0; mf < 4; mf++)                   \
    _Pragma("unroll") for (int nf = 0; nf < 2; nf++)                   \
    _Pragma("unroll") for (int ks = 0; ks < 2; ks++)                   \
      acc[MG][mf][(NFB) + nf] = __builtin_amdgcn_mfma_f32_16x16x32_bf16( \
          a[mf][ks], BB[nf][ks], acc[MG][mf][(NFB) + nf], 0, 0, 0);    \
    __builtin_amdgcn_s_setprio(0);                                     \
  } while (0)

  constexpr int NS = KDIM / 64;
  // prologue: tiles 0 and 1 fully staged (16 ops); vmcnt(8) -> tile0 landed.
  STAGE_A(0, 0, 0); STAGE_A(1, 1, 0); STAGE_B(0, 0, 0); STAGE_B(1, 1, 0);
  STAGE_B(2, 0, 1); STAGE_B(3, 1, 1); STAGE_A(2, 0, 1); STAGE_A(3, 1, 1);
  WAITV(8);
  SBAR();

#pragma unroll 2
  for (int t = 0; t < NS; ++t) {
    const int sa = (2 * t + wr) & 3;   // wave's A slot this tile
    const int sb = (2 * t + hb) & 3;   // wave's B slot this tile
    const int r0s = (2 * t) & 3, r1s = (2 * t + 1) & 3;  // restage slots (t+2)
    const bool st2 = (t + 2 < NS);
    // P1: A(mg0) + b0 + b1
    LDA03(sa);
    LDB2(b0, sb, 0);
    LDB2(b1, sb, 2);
    LGKM0(); SBAR();
    MFMAPH(0, b0, 0);
    // P2: A(mg1)
    LDA47(sa);
    LGKM0(); SBAR();
    MFMAPH(0, b1, 2);
    // P3: stage B(t+2) both halves (B slots last read P1, 2 barriers ago)
    if (st2) { STAGE_B(r0s, 0, t + 2); STAGE_B(r1s, 1, t + 2); }
    SBAR();
    MFMAPH(1, b1, 2);
    // P4: stage A(t+2); counted vmcnt -> tile t+1 landed; barrier; MFMA
    if (st2) { STAGE_A(r0s, 0, t + 2); STAGE_A(r1s, 1, t + 2); }
    if (st2) { WAITV(8); } else { WAITV(0); }
    SBAR();
    MFMAPH(1, b0, 0);
  }
#undef LDA03
#undef LDA47
#undef LDB2
#undef MFMAPH
#undef STAGE_A
#undef STAGE_B

  // epilogue: wave's contiguous 128x64 at (m0 + wr*128, n0 + wc*64)
  float bv[4];
#pragma unroll
  for (int nf = 0; nf < 4; nf++)
    bv[nf] = bias[(size_t)e * N + n0 + wc * 64 + nf * 16 + rsel];
#pragma unroll
  for (int mg = 0; mg < 2; mg++) {
#pragma unroll
    for (int mf = 0; mf < 4; mf++) {
#pragma unroll
      for (int r = 0; r < 4; r++) {
        const int grow = m0 + wr * 128 + mg * 64 + mf * 16 + lhi * 4 + r;
        if (grow < mlimit) {
          if constexpr (EPI == 0) {
            ushort* hrow = Hout + (size_t)grow * N + n0 + wc * 64;
#pragma unroll
            for (int nf = 0; nf < 4; nf++) {
              float v = acc[mg][mf][nf][r] + bv[nf];
              hrow[nf * 16 + rsel] = f2bf(fmaxf(v, 0.0f));
            }
          } else {
            const int tok = perm[grow];
            const float sc = pmaxArr[tok];
            float* yrow = Y + (size_t)tok * N + n0 + wc * 64;
#pragma unroll
            for (int nf = 0; nf < 4; nf++)
              yrow[nf * 16 + rsel] = (acc[mg][mf][nf][r] + bv[nf]) * sc;
          }
        }
      }
    }
  }
}

// ---------------------------------------------------------------------------
extern "C" void kernel_launch(void* const* d_in, const int* in_sizes, int n_in,
                              void* d_out, int out_size, void* d_ws, size_t ws_size,
                              hipStream_t stream) {
  const float* x  = (const float*)d_in[0];
  const float* sw = (const float*)d_in[1];
  const float* sb = (const float*)d_in[2];
  const float* w1 = (const float*)d_in[3];
  const float* b1 = (const float*)d_in[4];
  const float* w2 = (const float*)d_in[5];
  const float* b2 = (const float*)d_in[6];
  float* out = (float*)d_out;
  float* auxp = out + (size_t)NT * DOUT;

  char* wsb = (char*)d_ws;
  int*   cnt      = (int*)wsb;               // 8 ints
  float* probsum  = (float*)(wsb + 32);      // 8 floats
  int*   offsets  = (int*)(wsb + 64);        // 9 ints
  int*   routes   = (int*)(wsb + 256);
  int*   posArr   = routes + NT;
  float* pmaxArr  = (float*)(posArr + NT);
  int*   perm     = (int*)(pmaxArr + NT);
  ushort* Xg = (ushort*)(wsb + 256 + (size_t)4 * 4 * NT);           // [NT+256][DIN]
  ushort* Hg = Xg + (size_t)(NT + 256) * DIN;                       // [NT+256][DFF]
  ushort* Wt = Hg + (size_t)(NT + 256) * DFF;                       // E*DFF*DIN bf16, reused
  size_t needed = (size_t)((char*)Wt - wsb) + (size_t)NEXP * DFF * DIN * 2;
  if (ws_size < needed) return;  // insufficient scratch; fail validation visibly

  hipMemsetAsync(d_ws, 0, 64, stream);  // cnt + probsum

  router_kernel<<<NT / 64, 256, 0, stream>>>(x, sw, sb, routes, posArr, pmaxArr, cnt, probsum);
  offsets_aux_kernel<<<1, 64, 0, stream>>>(cnt, probsum, offsets, auxp);
  gather_kernel<<<NT / 4, 256, 0, stream>>>(x, routes, posArr, offsets, perm, Xg);

  // w1: [E][DIN][DFF] -> Wt [E][DFF][DIN]
  transpose_cvt_kernel<<<NEXP * (DIN / 64) * (DFF / 64), 256, 0, stream>>>(w1, Wt, DIN, DFF);
  // GEMM1: flat grid 1024 = 8e x 16bx x 8by, expert->XCD chunk swizzle.
  moe_gemm8p_kernel<DIN, 0><<<1024, 512, 0, stream>>>(
      Xg, Wt, b1, offsets, Hg, nullptr, nullptr, nullptr, DFF);

  // w2: [E][DFF][DOUT] -> Wt [E][DOUT][DFF]  (reuse Wt; stream-ordered)
  transpose_cvt_kernel<<<NEXP * (DFF / 64) * (DOUT / 64), 256, 0, stream>>>(w2, Wt, DFF, DOUT);
  // GEMM2: direct, ~128-136 live blocks.
  moe_gemm8p_kernel<DFF, 1><<<dim3(DOUT / 256, 8, NEXP), 512, 0, stream>>>(
      Hg, Wt, b2, offsets, nullptr, out, perm, pmaxArr, DOUT);
}